// Round 7
// baseline (468.561 us; speedup 1.0000x reference)
//
#include <hip/hip_runtime.h>
#include <hip/hip_bf16.h>

#define N_NODES 50000
#define N_EDGES 800000
#define DIM 128
#define NTILES (N_EDGES / 64)   // 12500 exactly
#define SCAN_B 196              // ceil(50000/256)
#define HIST_B 3125             // 800000/256
#define LIN1_B 782              // ceil(50000/64)
#define GRID1 512               // K1: 2 blocks/CU — huge co-residency margin (35KB LDS, <128 VGPR)

typedef __bf16 bf16x8 __attribute__((ext_vector_type(8)));
typedef float f32x4 __attribute__((ext_vector_type(4)));
typedef unsigned int u32x4 __attribute__((ext_vector_type(4)));

__device__ __forceinline__ unsigned short f2bf(float f) {
    unsigned u = __float_as_uint(f);
    u += 0x7fffu + ((u >> 16) & 1u);          // round-to-nearest-even
    return (unsigned short)(u >> 16);
}

// device-scope grid barrier: release fence -> arrive -> spin -> acquire fence
__device__ __forceinline__ void gridbar(unsigned int* bar, int phase) {
    __syncthreads();
    if (threadIdx.x == 0) {
        __threadfence();                       // release: publish this block's writes
        atomicAdd(&bar[phase], 1u);
        while (atomicAdd(&bar[phase], 0u) < (unsigned)GRID1)
            __builtin_amdgcn_s_sleep(2);
        __threadfence();                       // acquire: see other blocks' writes
    }
    __syncthreads();
}

// ---- K1: persistent sort+lin1. P0 zero+convert | P1 hist | P2 scan | P3 scatter+lin1
// identity: [h_i, h_j-h_i] @ W2 = h_i @ (W2a - W2b) + h_j @ W2b
__global__ __launch_bounds__(256, 2) void sort_lin1_kernel(
        const float* __restrict__ x, const int* __restrict__ eidx,
        const float* __restrict__ W1, const float* __restrict__ b1,
        const float* __restrict__ W2, const float* __restrict__ W3,
        unsigned short* __restrict__ W1t, unsigned short* __restrict__ Wat,
        unsigned short* __restrict__ Wbt, unsigned short* __restrict__ W3t,
        int* __restrict__ cnt, int* __restrict__ aux, unsigned int* __restrict__ bar,
        int2* __restrict__ spair, unsigned short* __restrict__ hbf,
        u32x4* __restrict__ outz) {
    __shared__ __align__(16) unsigned short w1t[128 * 136];   // 34.8 KB; head doubles as int scan buf
    int* buf = (int*)w1t;
    int tid = threadIdx.x, bid = blockIdx.x;
    int gid = bid * 256 + tid;

    // ---------------- P0: zero out+cnt, convert weights ----------------
    {
        u32x4 z = (u32x4){0u, 0u, 0u, 0u};
        for (int i = gid; i < N_NODES * DIM / 4; i += GRID1 * 256) outz[i] = z;   // 1.6M uint4
        if (gid < N_NODES) cnt[gid] = 0;          // GRID1*256 = 131072 > 50000
        if (gid < 4 * DIM * DIM) {                // 65536 < 131072
            int j = gid & (DIM * DIM - 1);
            int k = j >> 7, n = j & 127;
            int sec = gid >> 14;
            if (sec == 0)      W1t[n * 128 + k] = f2bf(W1[k * 128 + n]);
            else if (sec == 1) Wat[n * 128 + k] = f2bf(W2[k * 128 + n] - W2[(k + 128) * 128 + n]);
            else if (sec == 2) Wbt[n * 128 + k] = f2bf(W2[(k + 128) * 128 + n]);
            else               W3t[n * 128 + k] = f2bf(W3[k * 128 + n]);
        }
    }
    gridbar(bar, 0);

    // ---------------- P1: dst histogram ----------------
    for (int e = gid; e < N_EDGES; e += GRID1 * 256)
        atomicAdd(&cnt[eidx[N_EDGES + e]], 1);
    gridbar(bar, 1);

    // ---------------- P2: per-chunk exclusive scan + chunk totals ----------------
    if (bid < SCAN_B) {
        int i = bid * 256 + tid;
        int v = (i < N_NODES) ? cnt[i] : 0;
        buf[tid] = v;
        __syncthreads();
        for (int off = 1; off < 256; off <<= 1) {
            int u = (tid >= off) ? buf[tid - off] : 0;
            __syncthreads();
            buf[tid] += u;
            __syncthreads();
        }
        if (i < N_NODES) cnt[i] = buf[tid] - v;   // exclusive within chunk
        if (tid == 255) aux[bid] = buf[255];      // chunk total
    }
    gridbar(bar, 2);

    // ---------------- P3: local aux scan -> scatter -> lin1 ----------------
    {
        int v = (tid < SCAN_B) ? aux[tid] : 0;
        buf[tid] = v;
        __syncthreads();
        for (int off = 1; off < 256; off <<= 1) {
            int u = (tid >= off) ? buf[tid - off] : 0;
            __syncthreads();
            buf[tid] += u;
            __syncthreads();
        }
        int excl = buf[tid] - v;
        __syncthreads();
        buf[tid] = excl;
        __syncthreads();
        for (int ch = bid; ch < HIST_B; ch += GRID1) {
            int e = ch * 256 + tid;               // exactly covers 800000
            int d = eidx[N_EDGES + e];
            int p = atomicAdd(&cnt[d], 1) + buf[d >> 8];
            spair[p] = make_int2(eidx[e], d);
        }
    }
    __syncthreads();                              // scatter done reading buf before w1t overwrite
    {
        // lin1: hbf[N][128] = bf16(x @ W1 + b1)
        #pragma unroll
        for (int it = 0; it < 8; it++) {
            int idx = (tid + it * 256) * 8;
            int n = idx >> 7, k = idx & 127;
            *(u32x4*)(&w1t[n * 136 + k]) = *(const u32x4*)(&W1t[idx]);
        }
        __syncthreads();
        int w = tid >> 6, lane = tid & 63;
        int lr = lane & 15, q = lane >> 4;
        for (int bl = bid; bl < LIN1_B; bl += GRID1) {
            int row0 = bl * 64 + w * 16;
            int rowA = row0 + lr; if (rowA >= N_NODES) rowA = N_NODES - 1;
            f32x4 acc[8];
            #pragma unroll
            for (int ct = 0; ct < 8; ct++) acc[ct] = (f32x4){0.f, 0.f, 0.f, 0.f};
            #pragma unroll
            for (int kt = 0; kt < 4; kt++) {
                const float* ap = x + (size_t)rowA * DIM + kt * 32 + q * 8;
                f32x4 x0 = *(const f32x4*)(ap);
                f32x4 x1 = *(const f32x4*)(ap + 4);
                bf16x8 a;
                #pragma unroll
                for (int j = 0; j < 4; j++) { a[j] = (__bf16)x0[j]; a[j + 4] = (__bf16)x1[j]; }
                #pragma unroll
                for (int ct = 0; ct < 8; ct++) {
                    bf16x8 b = __builtin_bit_cast(bf16x8,
                        *(const u32x4*)(&w1t[(ct * 16 + lr) * 136 + kt * 32 + q * 8]));
                    acc[ct] = __builtin_amdgcn_mfma_f32_16x16x32_bf16(a, b, acc[ct], 0, 0, 0);
                }
            }
            #pragma unroll
            for (int ct = 0; ct < 8; ct++) {
                int col = ct * 16 + lr;
                float bias = b1[col];
                #pragma unroll
                for (int r = 0; r < 4; r++) {
                    int row = row0 + q * 4 + r;   // C/D: col=lane&15, row=quad*4+reg
                    if (row < N_NODES)
                        hbf[(size_t)row * DIM + col] = f2bf(acc[ct][r] + bias);
                }
            }
        }
    }
}

// ---- K2: fused edge MLP + segmented scatter-max (identical to R5's proven kernel)
__global__ __launch_bounds__(256, 3) void edge_kernel(
        const unsigned short* __restrict__ hbf,
        const int2* __restrict__ spair,
        const unsigned short* __restrict__ Wat,
        const unsigned short* __restrict__ Wbt,
        const unsigned short* __restrict__ W3t,
        const float* __restrict__ b2,
        const float* __restrict__ b3,
        unsigned int* __restrict__ out) {
    __shared__ __align__(16) unsigned short gbuf[2 * 64 * 136];  // hi|hj; reused as fp32 m2 [64][132]
    __shared__ __align__(16) unsigned short m1_lds[64 * 136];
    __shared__ int s_dst[64];

    unsigned short* hi_lds = gbuf;
    unsigned short* hj_lds = gbuf + 64 * 136;
    float* m2f = (float*)gbuf;

    int tid = threadIdx.x;
    int w = tid >> 6, lane = tid & 63;
    int lr = lane & 15, q = lane >> 4;
    int tr = tid >> 4;             // tile-row group 0..15
    int c = (tid & 15) * 8;        // col chunk (shorts)

    // register-cached B fragments (fixed cols per wave, amortized over grid-stride loop)
    bf16x8 baf[2][4], bbf[2][4], b3f[2][4];
    float b2v[2], b3v[2];
    #pragma unroll
    for (int ct = 0; ct < 2; ct++) {
        int n = (2 * w + ct) * 16 + lr;
        #pragma unroll
        for (int kt = 0; kt < 4; kt++) {
            baf[ct][kt] = __builtin_bit_cast(bf16x8, *(const u32x4*)(&Wat[n * 128 + kt * 32 + q * 8]));
            bbf[ct][kt] = __builtin_bit_cast(bf16x8, *(const u32x4*)(&Wbt[n * 128 + kt * 32 + q * 8]));
            b3f[ct][kt] = __builtin_bit_cast(bf16x8, *(const u32x4*)(&W3t[n * 128 + kt * 32 + q * 8]));
        }
        b2v[ct] = b2[n];
        b3v[ct] = b3[n];
    }

    int tb = blockIdx.x;
    int2 pr[4];
    {
        int eb = tb * 64;
        #pragma unroll
        for (int it = 0; it < 4; it++) pr[it] = spair[eb + tr + 16 * it];
    }

    for (; tb < NTILES; tb += gridDim.x) {
        // gather this tile straight to LDS (indices resident in pr)
        #pragma unroll
        for (int it = 0; it < 4; it++) {
            int t = tr + 16 * it;
            u32x4 gi = *(const u32x4*)(&hbf[(size_t)pr[it].y * DIM + c]);
            u32x4 gj = *(const u32x4*)(&hbf[(size_t)pr[it].x * DIM + c]);
            *(u32x4*)(&hi_lds[t * 136 + c]) = gi;
            *(u32x4*)(&hj_lds[t * 136 + c]) = gj;
        }
        if ((tid & 15) == 0) {
            #pragma unroll
            for (int it = 0; it < 4; it++) s_dst[tr + 16 * it] = pr[it].y;
        }
        __syncthreads();

        // prefetch next tile's indices (drains in the m1 barrier's slack)
        int nx = tb + (int)gridDim.x;
        int2 npr[4];
        if (nx < NTILES) {
            int eb = nx * 64;
            #pragma unroll
            for (int it = 0; it < 4; it++) npr[it] = spair[eb + tr + 16 * it];
        }

        // GEMM1: m1 = relu(h_i@Wa + h_j@Wb + b2)
        f32x4 acc1[4][2];
        #pragma unroll
        for (int rt = 0; rt < 4; rt++)
            #pragma unroll
            for (int ct = 0; ct < 2; ct++) acc1[rt][ct] = (f32x4){0.f, 0.f, 0.f, 0.f};
        #pragma unroll
        for (int kt = 0; kt < 4; kt++) {
            #pragma unroll
            for (int rt = 0; rt < 4; rt++) {
                bf16x8 ai = __builtin_bit_cast(bf16x8,
                    *(const u32x4*)(&hi_lds[(rt * 16 + lr) * 136 + kt * 32 + q * 8]));
                bf16x8 aj = __builtin_bit_cast(bf16x8,
                    *(const u32x4*)(&hj_lds[(rt * 16 + lr) * 136 + kt * 32 + q * 8]));
                acc1[rt][0] = __builtin_amdgcn_mfma_f32_16x16x32_bf16(ai, baf[0][kt], acc1[rt][0], 0, 0, 0);
                acc1[rt][1] = __builtin_amdgcn_mfma_f32_16x16x32_bf16(ai, baf[1][kt], acc1[rt][1], 0, 0, 0);
                acc1[rt][0] = __builtin_amdgcn_mfma_f32_16x16x32_bf16(aj, bbf[0][kt], acc1[rt][0], 0, 0, 0);
                acc1[rt][1] = __builtin_amdgcn_mfma_f32_16x16x32_bf16(aj, bbf[1][kt], acc1[rt][1], 0, 0, 0);
            }
        }
        #pragma unroll
        for (int rt = 0; rt < 4; rt++) {
            #pragma unroll
            for (int ct = 0; ct < 2; ct++) {
                int col = (2 * w + ct) * 16 + lr;
                #pragma unroll
                for (int r = 0; r < 4; r++) {
                    float v = fmaxf(acc1[rt][ct][r] + b2v[ct], 0.f);
                    m1_lds[(rt * 16 + q * 4 + r) * 136 + col] = f2bf(v);
                }
            }
        }
        __syncthreads();   // m1 ready; GEMM1 reads of gbuf done -> m2f reuse safe

        // GEMM2: m2 = relu(m1 @ W3 + b3)
        f32x4 acc2[4][2];
        #pragma unroll
        for (int rt = 0; rt < 4; rt++)
            #pragma unroll
            for (int ct = 0; ct < 2; ct++) acc2[rt][ct] = (f32x4){0.f, 0.f, 0.f, 0.f};
        #pragma unroll
        for (int kt = 0; kt < 4; kt++) {
            #pragma unroll
            for (int rt = 0; rt < 4; rt++) {
                bf16x8 a = __builtin_bit_cast(bf16x8,
                    *(const u32x4*)(&m1_lds[(rt * 16 + lr) * 136 + kt * 32 + q * 8]));
                acc2[rt][0] = __builtin_amdgcn_mfma_f32_16x16x32_bf16(a, b3f[0][kt], acc2[rt][0], 0, 0, 0);
                acc2[rt][1] = __builtin_amdgcn_mfma_f32_16x16x32_bf16(a, b3f[1][kt], acc2[rt][1], 0, 0, 0);
            }
        }
        #pragma unroll
        for (int rt = 0; rt < 4; rt++) {
            #pragma unroll
            for (int ct = 0; ct < 2; ct++) {
                int col = (2 * w + ct) * 16 + lr;
                #pragma unroll
                for (int r = 0; r < 4; r++) {
                    float v = fmaxf(acc2[rt][ct][r] + b3v[ct], 0.f);
                    m2f[(rt * 16 + q * 4 + r) * 132 + col] = v;
                }
            }
        }
        __syncthreads();

        // segmented max over sorted dst runs: thread -> (col = tid&127, rows r0..r0+31)
        {
            int col = tid & 127;
            int r0 = (tid >> 7) * 32;
            float cur = m2f[r0 * 132 + col];
            int d = s_dst[r0];                      // wave-uniform
            #pragma unroll 4
            for (int i = 1; i < 32; i++) {
                int dn = s_dst[r0 + i];             // wave-uniform
                float v = m2f[(r0 + i) * 132 + col];
                if (dn != d) {                      // wave-uniform branch
                    atomicMax(&out[(size_t)d * DIM + col], __float_as_uint(cur));
                    d = dn; cur = v;
                } else {
                    cur = fmaxf(cur, v);
                }
            }
            atomicMax(&out[(size_t)d * DIM + col], __float_as_uint(cur));
        }
        __syncthreads();   // protect s_dst/gbuf/m1_lds before next tile's gather commit

        #pragma unroll
        for (int it = 0; it < 4; it++) pr[it] = npr[it];
    }
}

extern "C" void kernel_launch(void* const* d_in, const int* in_sizes, int n_in,
                              void* d_out, int out_size, void* d_ws, size_t ws_size,
                              hipStream_t stream) {
    const float* x  = (const float*)d_in[0];
    const int* eidx = (const int*)d_in[1];
    const float* W1 = (const float*)d_in[2];
    const float* b1 = (const float*)d_in[3];
    const float* W2 = (const float*)d_in[4];
    const float* b2 = (const float*)d_in[5];
    const float* W3 = (const float*)d_in[6];
    const float* b3 = (const float*)d_in[7];

    char* ws = (char*)d_ws;
    unsigned short* hbf = (unsigned short*)ws;                     // 12,800,000 B
    unsigned short* W1t = (unsigned short*)(ws + 12800000);        // 32,768 B
    unsigned short* Wat = (unsigned short*)(ws + 12832768);        // 32,768 B
    unsigned short* Wbt = (unsigned short*)(ws + 12865536);        // 32,768 B
    unsigned short* W3t = (unsigned short*)(ws + 12898304);        // 32,768 B
    int* cnt            = (int*)(ws + 12931072);                   // 200,000 B
    int* aux            = (int*)(ws + 13131072);                   // 1,024 B
    unsigned int* bar   = (unsigned int*)(ws + 13132096);          // 64 B
    int2* spair         = (int2*)(ws + 13132160);                  // 6,400,000 B -> 19,532,160 total

    hipMemsetAsync(bar, 0, 64, stream);
    sort_lin1_kernel<<<GRID1, 256, 0, stream>>>(x, eidx, W1, b1, W2, W3,
        W1t, Wat, Wbt, W3t, cnt, aux, bar, spair, hbf, (u32x4*)d_out);
    edge_kernel<<<2048, 256, 0, stream>>>(hbf, spair, Wat, Wbt, W3t, b2, b3, (unsigned int*)d_out);
}

// Round 8
// 464.206 us; speedup vs baseline: 1.0094x; 1.0094x over previous
//
#include <hip/hip_runtime.h>
#include <hip/hip_bf16.h>

#define N_NODES 50000
#define N_EDGES 800000
#define DIM 128
#define NTILES (N_EDGES / 64)   // 12500 exactly
#define SCAN_B 196              // ceil(50000/256)
#define HIST_B 3125             // 800000/256
#define LIN1_B 782              // ceil(50000/64)
#define GRID1 512               // K1: 2 blocks/CU — huge co-residency margin (35KB LDS, <128 VGPR)

typedef __bf16 bf16x8 __attribute__((ext_vector_type(8)));
typedef float f32x4 __attribute__((ext_vector_type(4)));
typedef unsigned int u32x4 __attribute__((ext_vector_type(4)));

__device__ __forceinline__ unsigned short f2bf(float f) {
    unsigned u = __float_as_uint(f);
    u += 0x7fffu + ((u >> 16) & 1u);          // round-to-nearest-even
    return (unsigned short)(u >> 16);
}

// device-scope grid barrier. Arrive: one RMW per block. Spin: LOADS only
// (R7 lesson: RMW-polling one line serializes TCC ownership -> ~70us/barrier;
// read-only polls are L2-broadcast-served -> ~1-2us).
__device__ __forceinline__ void gridbar(unsigned int* bar, int phase) {
    __syncthreads();
    if (threadIdx.x == 0) {
        __hip_atomic_fetch_add(&bar[phase], 1u, __ATOMIC_RELEASE, __HIP_MEMORY_SCOPE_AGENT);
        while (__hip_atomic_load(&bar[phase], __ATOMIC_ACQUIRE, __HIP_MEMORY_SCOPE_AGENT)
               < (unsigned)GRID1)
            __builtin_amdgcn_s_sleep(8);
    }
    __syncthreads();
}

// ---- K1: persistent sort+lin1. P0 zero+convert | P1 hist | P2 scan | P3 scatter+lin1
// identity: [h_i, h_j-h_i] @ W2 = h_i @ (W2a - W2b) + h_j @ W2b
__global__ __launch_bounds__(256, 2) void sort_lin1_kernel(
        const float* __restrict__ x, const int* __restrict__ eidx,
        const float* __restrict__ W1, const float* __restrict__ b1,
        const float* __restrict__ W2, const float* __restrict__ W3,
        unsigned short* __restrict__ W1t, unsigned short* __restrict__ Wat,
        unsigned short* __restrict__ Wbt, unsigned short* __restrict__ W3t,
        int* __restrict__ cnt, int* __restrict__ aux, unsigned int* __restrict__ bar,
        int2* __restrict__ spair, unsigned short* __restrict__ hbf,
        u32x4* __restrict__ outz) {
    __shared__ __align__(16) unsigned short w1t[128 * 136];   // 34.8 KB; head doubles as int scan buf
    int* buf = (int*)w1t;
    int tid = threadIdx.x, bid = blockIdx.x;
    int gid = bid * 256 + tid;

    // ---------------- P0: zero out+cnt, convert weights ----------------
    {
        u32x4 z = (u32x4){0u, 0u, 0u, 0u};
        for (int i = gid; i < N_NODES * DIM / 4; i += GRID1 * 256) outz[i] = z;   // 1.6M uint4
        if (gid < N_NODES) cnt[gid] = 0;          // GRID1*256 = 131072 > 50000
        if (gid < 4 * DIM * DIM) {                // 65536 < 131072
            int j = gid & (DIM * DIM - 1);
            int k = j >> 7, n = j & 127;
            int sec = gid >> 14;
            if (sec == 0)      W1t[n * 128 + k] = f2bf(W1[k * 128 + n]);
            else if (sec == 1) Wat[n * 128 + k] = f2bf(W2[k * 128 + n] - W2[(k + 128) * 128 + n]);
            else if (sec == 2) Wbt[n * 128 + k] = f2bf(W2[(k + 128) * 128 + n]);
            else               W3t[n * 128 + k] = f2bf(W3[k * 128 + n]);
        }
    }
    gridbar(bar, 0);

    // ---------------- P1: dst histogram ----------------
    for (int e = gid; e < N_EDGES; e += GRID1 * 256)
        atomicAdd(&cnt[eidx[N_EDGES + e]], 1);
    gridbar(bar, 1);

    // ---------------- P2: per-chunk exclusive scan + chunk totals ----------------
    if (bid < SCAN_B) {
        int i = bid * 256 + tid;
        int v = (i < N_NODES) ? cnt[i] : 0;
        buf[tid] = v;
        __syncthreads();
        for (int off = 1; off < 256; off <<= 1) {
            int u = (tid >= off) ? buf[tid - off] : 0;
            __syncthreads();
            buf[tid] += u;
            __syncthreads();
        }
        if (i < N_NODES) cnt[i] = buf[tid] - v;   // exclusive within chunk
        if (tid == 255) aux[bid] = buf[255];      // chunk total
    }
    gridbar(bar, 2);

    // ---------------- P3: local aux scan -> scatter -> lin1 ----------------
    {
        int v = (tid < SCAN_B) ? aux[tid] : 0;
        buf[tid] = v;
        __syncthreads();
        for (int off = 1; off < 256; off <<= 1) {
            int u = (tid >= off) ? buf[tid - off] : 0;
            __syncthreads();
            buf[tid] += u;
            __syncthreads();
        }
        int excl = buf[tid] - v;
        __syncthreads();
        buf[tid] = excl;
        __syncthreads();
        for (int ch = bid; ch < HIST_B; ch += GRID1) {
            int e = ch * 256 + tid;               // exactly covers 800000
            int d = eidx[N_EDGES + e];
            int p = atomicAdd(&cnt[d], 1) + buf[d >> 8];
            spair[p] = make_int2(eidx[e], d);
        }
    }
    __syncthreads();                              // scatter done reading buf before w1t overwrite
    {
        // lin1: hbf[N][128] = bf16(x @ W1 + b1)
        #pragma unroll
        for (int it = 0; it < 8; it++) {
            int idx = (tid + it * 256) * 8;
            int n = idx >> 7, k = idx & 127;
            *(u32x4*)(&w1t[n * 136 + k]) = *(const u32x4*)(&W1t[idx]);
        }
        __syncthreads();
        int w = tid >> 6, lane = tid & 63;
        int lr = lane & 15, q = lane >> 4;
        for (int bl = bid; bl < LIN1_B; bl += GRID1) {
            int row0 = bl * 64 + w * 16;
            int rowA = row0 + lr; if (rowA >= N_NODES) rowA = N_NODES - 1;
            f32x4 acc[8];
            #pragma unroll
            for (int ct = 0; ct < 8; ct++) acc[ct] = (f32x4){0.f, 0.f, 0.f, 0.f};
            #pragma unroll
            for (int kt = 0; kt < 4; kt++) {
                const float* ap = x + (size_t)rowA * DIM + kt * 32 + q * 8;
                f32x4 x0 = *(const f32x4*)(ap);
                f32x4 x1 = *(const f32x4*)(ap + 4);
                bf16x8 a;
                #pragma unroll
                for (int j = 0; j < 4; j++) { a[j] = (__bf16)x0[j]; a[j + 4] = (__bf16)x1[j]; }
                #pragma unroll
                for (int ct = 0; ct < 8; ct++) {
                    bf16x8 b = __builtin_bit_cast(bf16x8,
                        *(const u32x4*)(&w1t[(ct * 16 + lr) * 136 + kt * 32 + q * 8]));
                    acc[ct] = __builtin_amdgcn_mfma_f32_16x16x32_bf16(a, b, acc[ct], 0, 0, 0);
                }
            }
            #pragma unroll
            for (int ct = 0; ct < 8; ct++) {
                int col = ct * 16 + lr;
                float bias = b1[col];
                #pragma unroll
                for (int r = 0; r < 4; r++) {
                    int row = row0 + q * 4 + r;   // C/D: col=lane&15, row=quad*4+reg
                    if (row < N_NODES)
                        hbf[(size_t)row * DIM + col] = f2bf(acc[ct][r] + bias);
                }
            }
        }
    }
}

// ---- K2: fused edge MLP + segmented scatter-max (identical to R5's proven kernel)
__global__ __launch_bounds__(256, 3) void edge_kernel(
        const unsigned short* __restrict__ hbf,
        const int2* __restrict__ spair,
        const unsigned short* __restrict__ Wat,
        const unsigned short* __restrict__ Wbt,
        const unsigned short* __restrict__ W3t,
        const float* __restrict__ b2,
        const float* __restrict__ b3,
        unsigned int* __restrict__ out) {
    __shared__ __align__(16) unsigned short gbuf[2 * 64 * 136];  // hi|hj; reused as fp32 m2 [64][132]
    __shared__ __align__(16) unsigned short m1_lds[64 * 136];
    __shared__ int s_dst[64];

    unsigned short* hi_lds = gbuf;
    unsigned short* hj_lds = gbuf + 64 * 136;
    float* m2f = (float*)gbuf;

    int tid = threadIdx.x;
    int w = tid >> 6, lane = tid & 63;
    int lr = lane & 15, q = lane >> 4;
    int tr = tid >> 4;             // tile-row group 0..15
    int c = (tid & 15) * 8;        // col chunk (shorts)

    // register-cached B fragments (fixed cols per wave, amortized over grid-stride loop)
    bf16x8 baf[2][4], bbf[2][4], b3f[2][4];
    float b2v[2], b3v[2];
    #pragma unroll
    for (int ct = 0; ct < 2; ct++) {
        int n = (2 * w + ct) * 16 + lr;
        #pragma unroll
        for (int kt = 0; kt < 4; kt++) {
            baf[ct][kt] = __builtin_bit_cast(bf16x8, *(const u32x4*)(&Wat[n * 128 + kt * 32 + q * 8]));
            bbf[ct][kt] = __builtin_bit_cast(bf16x8, *(const u32x4*)(&Wbt[n * 128 + kt * 32 + q * 8]));
            b3f[ct][kt] = __builtin_bit_cast(bf16x8, *(const u32x4*)(&W3t[n * 128 + kt * 32 + q * 8]));
        }
        b2v[ct] = b2[n];
        b3v[ct] = b3[n];
    }

    int tb = blockIdx.x;
    int2 pr[4];
    {
        int eb = tb * 64;
        #pragma unroll
        for (int it = 0; it < 4; it++) pr[it] = spair[eb + tr + 16 * it];
    }

    for (; tb < NTILES; tb += gridDim.x) {
        // gather this tile straight to LDS (indices resident in pr)
        #pragma unroll
        for (int it = 0; it < 4; it++) {
            int t = tr + 16 * it;
            u32x4 gi = *(const u32x4*)(&hbf[(size_t)pr[it].y * DIM + c]);
            u32x4 gj = *(const u32x4*)(&hbf[(size_t)pr[it].x * DIM + c]);
            *(u32x4*)(&hi_lds[t * 136 + c]) = gi;
            *(u32x4*)(&hj_lds[t * 136 + c]) = gj;
        }
        if ((tid & 15) == 0) {
            #pragma unroll
            for (int it = 0; it < 4; it++) s_dst[tr + 16 * it] = pr[it].y;
        }
        __syncthreads();

        // prefetch next tile's indices (drains in the m1 barrier's slack)
        int nx = tb + (int)gridDim.x;
        int2 npr[4];
        if (nx < NTILES) {
            int eb = nx * 64;
            #pragma unroll
            for (int it = 0; it < 4; it++) npr[it] = spair[eb + tr + 16 * it];
        }

        // GEMM1: m1 = relu(h_i@Wa + h_j@Wb + b2)
        f32x4 acc1[4][2];
        #pragma unroll
        for (int rt = 0; rt < 4; rt++)
            #pragma unroll
            for (int ct = 0; ct < 2; ct++) acc1[rt][ct] = (f32x4){0.f, 0.f, 0.f, 0.f};
        #pragma unroll
        for (int kt = 0; kt < 4; kt++) {
            #pragma unroll
            for (int rt = 0; rt < 4; rt++) {
                bf16x8 ai = __builtin_bit_cast(bf16x8,
                    *(const u32x4*)(&hi_lds[(rt * 16 + lr) * 136 + kt * 32 + q * 8]));
                bf16x8 aj = __builtin_bit_cast(bf16x8,
                    *(const u32x4*)(&hj_lds[(rt * 16 + lr) * 136 + kt * 32 + q * 8]));
                acc1[rt][0] = __builtin_amdgcn_mfma_f32_16x16x32_bf16(ai, baf[0][kt], acc1[rt][0], 0, 0, 0);
                acc1[rt][1] = __builtin_amdgcn_mfma_f32_16x16x32_bf16(ai, baf[1][kt], acc1[rt][1], 0, 0, 0);
                acc1[rt][0] = __builtin_amdgcn_mfma_f32_16x16x32_bf16(aj, bbf[0][kt], acc1[rt][0], 0, 0, 0);
                acc1[rt][1] = __builtin_amdgcn_mfma_f32_16x16x32_bf16(aj, bbf[1][kt], acc1[rt][1], 0, 0, 0);
            }
        }
        #pragma unroll
        for (int rt = 0; rt < 4; rt++) {
            #pragma unroll
            for (int ct = 0; ct < 2; ct++) {
                int col = (2 * w + ct) * 16 + lr;
                #pragma unroll
                for (int r = 0; r < 4; r++) {
                    float v = fmaxf(acc1[rt][ct][r] + b2v[ct], 0.f);
                    m1_lds[(rt * 16 + q * 4 + r) * 136 + col] = f2bf(v);
                }
            }
        }
        __syncthreads();   // m1 ready; GEMM1 reads of gbuf done -> m2f reuse safe

        // GEMM2: m2 = relu(m1 @ W3 + b3)
        f32x4 acc2[4][2];
        #pragma unroll
        for (int rt = 0; rt < 4; rt++)
            #pragma unroll
            for (int ct = 0; ct < 2; ct++) acc2[rt][ct] = (f32x4){0.f, 0.f, 0.f, 0.f};
        #pragma unroll
        for (int kt = 0; kt < 4; kt++) {
            #pragma unroll
            for (int rt = 0; rt < 4; rt++) {
                bf16x8 a = __builtin_bit_cast(bf16x8,
                    *(const u32x4*)(&m1_lds[(rt * 16 + lr) * 136 + kt * 32 + q * 8]));
                acc2[rt][0] = __builtin_amdgcn_mfma_f32_16x16x32_bf16(a, b3f[0][kt], acc2[rt][0], 0, 0, 0);
                acc2[rt][1] = __builtin_amdgcn_mfma_f32_16x16x32_bf16(a, b3f[1][kt], acc2[rt][1], 0, 0, 0);
            }
        }
        #pragma unroll
        for (int rt = 0; rt < 4; rt++) {
            #pragma unroll
            for (int ct = 0; ct < 2; ct++) {
                int col = (2 * w + ct) * 16 + lr;
                #pragma unroll
                for (int r = 0; r < 4; r++) {
                    float v = fmaxf(acc2[rt][ct][r] + b3v[ct], 0.f);
                    m2f[(rt * 16 + q * 4 + r) * 132 + col] = v;
                }
            }
        }
        __syncthreads();

        // segmented max over sorted dst runs: thread -> (col = tid&127, rows r0..r0+31)
        {
            int col = tid & 127;
            int r0 = (tid >> 7) * 32;
            float cur = m2f[r0 * 132 + col];
            int d = s_dst[r0];                      // wave-uniform
            #pragma unroll 4
            for (int i = 1; i < 32; i++) {
                int dn = s_dst[r0 + i];             // wave-uniform
                float v = m2f[(r0 + i) * 132 + col];
                if (dn != d) {                      // wave-uniform branch
                    atomicMax(&out[(size_t)d * DIM + col], __float_as_uint(cur));
                    d = dn; cur = v;
                } else {
                    cur = fmaxf(cur, v);
                }
            }
            atomicMax(&out[(size_t)d * DIM + col], __float_as_uint(cur));
        }
        __syncthreads();   // protect s_dst/gbuf/m1_lds before next tile's gather commit

        #pragma unroll
        for (int it = 0; it < 4; it++) pr[it] = npr[it];
    }
}

extern "C" void kernel_launch(void* const* d_in, const int* in_sizes, int n_in,
                              void* d_out, int out_size, void* d_ws, size_t ws_size,
                              hipStream_t stream) {
    const float* x  = (const float*)d_in[0];
    const int* eidx = (const int*)d_in[1];
    const float* W1 = (const float*)d_in[2];
    const float* b1 = (const float*)d_in[3];
    const float* W2 = (const float*)d_in[4];
    const float* b2 = (const float*)d_in[5];
    const float* W3 = (const float*)d_in[6];
    const float* b3 = (const float*)d_in[7];

    char* ws = (char*)d_ws;
    unsigned short* hbf = (unsigned short*)ws;                     // 12,800,000 B
    unsigned short* W1t = (unsigned short*)(ws + 12800000);        // 32,768 B
    unsigned short* Wat = (unsigned short*)(ws + 12832768);        // 32,768 B
    unsigned short* Wbt = (unsigned short*)(ws + 12865536);        // 32,768 B
    unsigned short* W3t = (unsigned short*)(ws + 12898304);        // 32,768 B
    int* cnt            = (int*)(ws + 12931072);                   // 200,000 B
    int* aux            = (int*)(ws + 13131072);                   // 1,024 B
    unsigned int* bar   = (unsigned int*)(ws + 13132096);          // 64 B
    int2* spair         = (int2*)(ws + 13132160);                  // 6,400,000 B -> 19,532,160 total

    hipMemsetAsync(bar, 0, 64, stream);
    sort_lin1_kernel<<<GRID1, 256, 0, stream>>>(x, eidx, W1, b1, W2, W3,
        W1t, Wat, Wbt, W3t, cnt, aux, bar, spair, hbf, (u32x4*)d_out);
    edge_kernel<<<2048, 256, 0, stream>>>(hbf, spair, Wat, Wbt, W3t, b2, b3, (unsigned int*)d_out);
}

// Round 9
// 293.089 us; speedup vs baseline: 1.5987x; 1.5838x over previous
//
#include <hip/hip_runtime.h>
#include <hip/hip_bf16.h>

#define N_NODES 50000
#define N_EDGES 800000
#define DIM 128
#define NTILES (N_EDGES / 64)   // 12500 exactly
#define SCAN_B 196              // ceil(50000/256)
#define HIST_B 3125             // 800000/256
#define NODE_B 782              // ceil(50000/64)
#define OUTZ_B 512

typedef __bf16 bf16x8 __attribute__((ext_vector_type(8)));
typedef float f32x4 __attribute__((ext_vector_type(4)));
typedef unsigned int u32x4 __attribute__((ext_vector_type(4)));

__device__ __forceinline__ unsigned short f2bf(float f) {
    unsigned u = __float_as_uint(f);
    u += 0x7fffu + ((u >> 16) & 1u);          // round-to-nearest-even
    return (unsigned short)(u >> 16);
}
__device__ __forceinline__ float bf2f(unsigned short s) {
    return __uint_as_float(((unsigned)s) << 16);
}

// ---- K1: convert weights (blocks 0..255) + dst hist (256..3380) + zero out (rest)
__global__ void prep_kernel(const float* __restrict__ W1, const float* __restrict__ W2,
                            const float* __restrict__ W3, const int* __restrict__ eidx,
                            unsigned short* __restrict__ W1t, unsigned short* __restrict__ Wat,
                            unsigned short* __restrict__ Wbt, unsigned short* __restrict__ W3t,
                            int* __restrict__ cnt, u32x4* __restrict__ outz) {
    int bid = blockIdx.x, tid = threadIdx.x;
    if (bid < 256) {
        int i = bid * 256 + tid;
        int j = i & (DIM * DIM - 1);
        int k = j >> 7, n = j & 127;
        int sec = i >> 14;
        if (sec == 0)      W1t[n * 128 + k] = f2bf(W1[k * 128 + n]);
        else if (sec == 1) Wat[n * 128 + k] = f2bf(W2[k * 128 + n] - W2[(k + 128) * 128 + n]);
        else if (sec == 2) Wbt[n * 128 + k] = f2bf(W2[(k + 128) * 128 + n]);
        else               W3t[n * 128 + k] = f2bf(W3[k * 128 + n]);
    } else if (bid < 256 + HIST_B) {
        int e = (bid - 256) * 256 + tid;      // exactly covers 800000
        atomicAdd(&cnt[eidx[N_EDGES + e]], 1);
    } else {
        int b = bid - 256 - HIST_B;
        u32x4 z = (u32x4){0u, 0u, 0u, 0u};
        for (int i = b * 256 + tid; i < N_NODES * DIM / 4; i += OUTZ_B * 256) outz[i] = z;
    }
}

// ---- K2: per-chunk exclusive scan of cnt + chunk totals
__global__ void scanA_kernel(int* __restrict__ cnt, int* __restrict__ aux) {
    __shared__ int buf[256];
    int t = threadIdx.x, i = blockIdx.x * 256 + t;
    int v = (i < N_NODES) ? cnt[i] : 0;
    buf[t] = v;
    __syncthreads();
    for (int off = 1; off < 256; off <<= 1) {
        int u = (t >= off) ? buf[t - off] : 0;
        __syncthreads();
        buf[t] += u;
        __syncthreads();
    }
    if (i < N_NODES) cnt[i] = buf[t] - v;
    if (t == 255) aux[blockIdx.x] = buf[255];
}

// ---- K3: scatter (blocks 0..3124) + node GEMMs (blocks 3125..3906)
// node part: h = bf16(x@W1+b1) -> LDS -> gA = bf16(h@Wa + b2), gB = bf16(h@Wb)
// where Wa = W2a - W2b, Wb = W2b, so edge m1 = relu(gA[dst] + gB[src]).
__global__ __launch_bounds__(256, 2) void scatter_node_kernel(
        const int* __restrict__ eidx, int* __restrict__ cursor, const int* __restrict__ aux,
        int2* __restrict__ spair,
        const float* __restrict__ x, const unsigned short* __restrict__ W1t,
        const unsigned short* __restrict__ Wat, const unsigned short* __restrict__ Wbt,
        const float* __restrict__ b1, const float* __restrict__ b2,
        unsigned short* __restrict__ gA, unsigned short* __restrict__ gB) {
    __shared__ __align__(16) unsigned short w1t[128 * 136];   // also scan buf for scatter path
    __shared__ __align__(16) unsigned short h_lds[64 * 136];
    int tid = threadIdx.x, bid = blockIdx.x;
    if (bid < HIST_B) {
        int* buf = (int*)w1t;
        int v = (tid < SCAN_B) ? aux[tid] : 0;
        buf[tid] = v;
        __syncthreads();
        for (int off = 1; off < 256; off <<= 1) {
            int u = (tid >= off) ? buf[tid - off] : 0;
            __syncthreads();
            buf[tid] += u;
            __syncthreads();
        }
        int excl = buf[tid] - v;
        __syncthreads();
        buf[tid] = excl;
        __syncthreads();
        int e = bid * 256 + tid;                  // exactly covers 800000
        int d = eidx[N_EDGES + e];
        int p = atomicAdd(&cursor[d], 1) + buf[d >> 8];
        spair[p] = make_int2(eidx[e], d);
        return;
    }
    // ---- node path
    int bl = bid - HIST_B;
    #pragma unroll
    for (int it = 0; it < 8; it++) {
        int idx = (tid + it * 256) * 8;
        int n = idx >> 7, k = idx & 127;
        *(u32x4*)(&w1t[n * 136 + k]) = *(const u32x4*)(&W1t[idx]);
    }
    int w = tid >> 6, lane = tid & 63;
    int lr = lane & 15, q = lane >> 4;
    // Wa/Wb B-frags: wave covers cols (2w+ct)*16+lr
    bf16x8 baf[2][4], bbf[2][4];
    float b2v[2];
    #pragma unroll
    for (int ct = 0; ct < 2; ct++) {
        int n = (2 * w + ct) * 16 + lr;
        #pragma unroll
        for (int kt = 0; kt < 4; kt++) {
            baf[ct][kt] = __builtin_bit_cast(bf16x8, *(const u32x4*)(&Wat[n * 128 + kt * 32 + q * 8]));
            bbf[ct][kt] = __builtin_bit_cast(bf16x8, *(const u32x4*)(&Wbt[n * 128 + kt * 32 + q * 8]));
        }
        b2v[ct] = b2[n];
    }
    __syncthreads();
    // stage 1: h rows (wave w: rows w*16..w*16+15 of this 64-row tile)
    int row0 = bl * 64;
    int rowA = row0 + w * 16 + lr; if (rowA >= N_NODES) rowA = N_NODES - 1;
    {
        f32x4 acc[8];
        #pragma unroll
        for (int ct = 0; ct < 8; ct++) acc[ct] = (f32x4){0.f, 0.f, 0.f, 0.f};
        #pragma unroll
        for (int kt = 0; kt < 4; kt++) {
            const float* ap = x + (size_t)rowA * DIM + kt * 32 + q * 8;
            f32x4 x0 = *(const f32x4*)(ap);
            f32x4 x1 = *(const f32x4*)(ap + 4);
            bf16x8 a;
            #pragma unroll
            for (int j = 0; j < 4; j++) { a[j] = (__bf16)x0[j]; a[j + 4] = (__bf16)x1[j]; }
            #pragma unroll
            for (int ct = 0; ct < 8; ct++) {
                bf16x8 b = __builtin_bit_cast(bf16x8,
                    *(const u32x4*)(&w1t[(ct * 16 + lr) * 136 + kt * 32 + q * 8]));
                acc[ct] = __builtin_amdgcn_mfma_f32_16x16x32_bf16(a, b, acc[ct], 0, 0, 0);
            }
        }
        #pragma unroll
        for (int ct = 0; ct < 8; ct++) {
            int col = ct * 16 + lr;
            float bias = b1[col];
            #pragma unroll
            for (int r = 0; r < 4; r++)   // C/D: col=lane&15, row=quad*4+reg
                h_lds[(w * 16 + q * 4 + r) * 136 + col] = f2bf(acc[ct][r] + bias);
        }
    }
    __syncthreads();
    // stage 2: gA/gB = h @ Wa|Wb over all 64 rows, wave's 32 cols
    {
        f32x4 accA[4][2], accB[4][2];
        #pragma unroll
        for (int rt = 0; rt < 4; rt++)
            #pragma unroll
            for (int ct = 0; ct < 2; ct++) {
                accA[rt][ct] = (f32x4){0.f, 0.f, 0.f, 0.f};
                accB[rt][ct] = (f32x4){0.f, 0.f, 0.f, 0.f};
            }
        #pragma unroll
        for (int kt = 0; kt < 4; kt++) {
            #pragma unroll
            for (int rt = 0; rt < 4; rt++) {
                bf16x8 a = __builtin_bit_cast(bf16x8,
                    *(const u32x4*)(&h_lds[(rt * 16 + lr) * 136 + kt * 32 + q * 8]));
                accA[rt][0] = __builtin_amdgcn_mfma_f32_16x16x32_bf16(a, baf[0][kt], accA[rt][0], 0, 0, 0);
                accA[rt][1] = __builtin_amdgcn_mfma_f32_16x16x32_bf16(a, baf[1][kt], accA[rt][1], 0, 0, 0);
                accB[rt][0] = __builtin_amdgcn_mfma_f32_16x16x32_bf16(a, bbf[0][kt], accB[rt][0], 0, 0, 0);
                accB[rt][1] = __builtin_amdgcn_mfma_f32_16x16x32_bf16(a, bbf[1][kt], accB[rt][1], 0, 0, 0);
            }
        }
        #pragma unroll
        for (int rt = 0; rt < 4; rt++) {
            #pragma unroll
            for (int ct = 0; ct < 2; ct++) {
                int col = (2 * w + ct) * 16 + lr;
                #pragma unroll
                for (int r = 0; r < 4; r++) {
                    int row = row0 + rt * 16 + q * 4 + r;
                    if (row < N_NODES) {
                        gA[(size_t)row * DIM + col] = f2bf(accA[rt][ct][r] + b2v[ct]);
                        gB[(size_t)row * DIM + col] = f2bf(accB[rt][ct][r]);
                    }
                }
            }
        }
    }
}

// ---- K4: edge = relu(gA[dst]+gB[src]) -> GEMM2 -> segmented scatter-max
__global__ __launch_bounds__(256, 4) void edge_kernel(
        const unsigned short* __restrict__ gA,
        const unsigned short* __restrict__ gB,
        const int2* __restrict__ spair,
        const unsigned short* __restrict__ W3t,
        const float* __restrict__ b3,
        unsigned int* __restrict__ out) {
    __shared__ __align__(16) unsigned short m1_lds[64 * 136];   // bf16 m1
    __shared__ __align__(16) unsigned short m2_lds[64 * 136];   // bf16 m2 (separate: no alias race)
    __shared__ int s_dst[64];

    int tid = threadIdx.x;
    int w = tid >> 6, lane = tid & 63;
    int lr = lane & 15, q = lane >> 4;
    int tr = tid >> 4;             // tile-row group 0..15
    int c = (tid & 15) * 8;        // col chunk (shorts)

    bf16x8 b3f[2][4];
    float b3v[2];
    #pragma unroll
    for (int ct = 0; ct < 2; ct++) {
        int n = (2 * w + ct) * 16 + lr;
        #pragma unroll
        for (int kt = 0; kt < 4; kt++)
            b3f[ct][kt] = __builtin_bit_cast(bf16x8, *(const u32x4*)(&W3t[n * 128 + kt * 32 + q * 8]));
        b3v[ct] = b3[n];
    }

    int tb = blockIdx.x;
    int2 pr[4];
    {
        int eb = tb * 64;
        #pragma unroll
        for (int it = 0; it < 4; it++) pr[it] = spair[eb + tr + 16 * it];
    }

    for (; tb < NTILES; tb += gridDim.x) {
        // m1[t][c..c+7] = relu(gA[dst_t] + gB[src_t])  — no GEMM1 at all
        #pragma unroll
        for (int it = 0; it < 4; it++) {
            int t = tr + 16 * it;
            u32x4 ga = *(const u32x4*)(&gA[(size_t)pr[it].y * DIM + c]);
            u32x4 gb = *(const u32x4*)(&gB[(size_t)pr[it].x * DIM + c]);
            u32x4 m;
            #pragma unroll
            for (int jj = 0; jj < 4; jj++) {
                float lo = fmaxf(__uint_as_float(ga[jj] << 16) + __uint_as_float(gb[jj] << 16), 0.f);
                float hi = fmaxf(__uint_as_float(ga[jj] & 0xffff0000u) + __uint_as_float(gb[jj] & 0xffff0000u), 0.f);
                m[jj] = (unsigned)f2bf(lo) | ((unsigned)f2bf(hi) << 16);
            }
            *(u32x4*)(&m1_lds[t * 136 + c]) = m;
        }
        if ((tid & 15) == 0) {
            #pragma unroll
            for (int it = 0; it < 4; it++) s_dst[tr + 16 * it] = pr[it].y;
        }
        __syncthreads();

        // prefetch next tile's indices
        int nx = tb + (int)gridDim.x;
        int2 npr[4];
        if (nx < NTILES) {
            int eb = nx * 64;
            #pragma unroll
            for (int it = 0; it < 4; it++) npr[it] = spair[eb + tr + 16 * it];
        }

        // GEMM2: m2 = relu(m1 @ W3 + b3)
        f32x4 acc2[4][2];
        #pragma unroll
        for (int rt = 0; rt < 4; rt++)
            #pragma unroll
            for (int ct = 0; ct < 2; ct++) acc2[rt][ct] = (f32x4){0.f, 0.f, 0.f, 0.f};
        #pragma unroll
        for (int kt = 0; kt < 4; kt++) {
            #pragma unroll
            for (int rt = 0; rt < 4; rt++) {
                bf16x8 a = __builtin_bit_cast(bf16x8,
                    *(const u32x4*)(&m1_lds[(rt * 16 + lr) * 136 + kt * 32 + q * 8]));
                acc2[rt][0] = __builtin_amdgcn_mfma_f32_16x16x32_bf16(a, b3f[0][kt], acc2[rt][0], 0, 0, 0);
                acc2[rt][1] = __builtin_amdgcn_mfma_f32_16x16x32_bf16(a, b3f[1][kt], acc2[rt][1], 0, 0, 0);
            }
        }
        #pragma unroll
        for (int rt = 0; rt < 4; rt++) {
            #pragma unroll
            for (int ct = 0; ct < 2; ct++) {
                int col = (2 * w + ct) * 16 + lr;
                #pragma unroll
                for (int r = 0; r < 4; r++)
                    m2_lds[(rt * 16 + q * 4 + r) * 136 + col] = f2bf(fmaxf(acc2[rt][ct][r] + b3v[ct], 0.f));
            }
        }
        __syncthreads();

        // segmented max over sorted dst runs: thread -> (col = tid&127, rows r0..r0+31)
        {
            int col = tid & 127;
            int r0 = (tid >> 7) * 32;
            float cur = bf2f(m2_lds[r0 * 136 + col]);
            int d = s_dst[r0];                      // wave-uniform
            #pragma unroll 4
            for (int i = 1; i < 32; i++) {
                int dn = s_dst[r0 + i];             // wave-uniform
                float v = bf2f(m2_lds[(r0 + i) * 136 + col]);
                if (dn != d) {                      // wave-uniform branch
                    atomicMax(&out[(size_t)d * DIM + col], __float_as_uint(cur));
                    d = dn; cur = v;
                } else {
                    cur = fmaxf(cur, v);
                }
            }
            atomicMax(&out[(size_t)d * DIM + col], __float_as_uint(cur));
        }
        __syncthreads();   // protect s_dst/m1/m2 before next tile

        #pragma unroll
        for (int it = 0; it < 4; it++) pr[it] = npr[it];
    }
}

extern "C" void kernel_launch(void* const* d_in, const int* in_sizes, int n_in,
                              void* d_out, int out_size, void* d_ws, size_t ws_size,
                              hipStream_t stream) {
    const float* x  = (const float*)d_in[0];
    const int* eidx = (const int*)d_in[1];
    const float* W1 = (const float*)d_in[2];
    const float* b1 = (const float*)d_in[3];
    const float* W2 = (const float*)d_in[4];
    const float* b2 = (const float*)d_in[5];
    const float* W3 = (const float*)d_in[6];
    const float* b3 = (const float*)d_in[7];

    char* ws = (char*)d_ws;
    unsigned short* gA  = (unsigned short*)ws;                     // 12,800,000 B
    unsigned short* gB  = (unsigned short*)(ws + 12800000);        // 12,800,000 B
    unsigned short* W1t = (unsigned short*)(ws + 25600000);        // 32,768 B
    unsigned short* Wat = (unsigned short*)(ws + 25632768);        // 32,768 B
    unsigned short* Wbt = (unsigned short*)(ws + 25665536);        // 32,768 B
    unsigned short* W3t = (unsigned short*)(ws + 25698304);        // 32,768 B
    int* cnt            = (int*)(ws + 25731072);                   // 200,000 B
    int* aux            = (int*)(ws + 25931072);                   // 1,024 B
    int2* spair         = (int2*)(ws + 25932096);                  // 6,400,000 B -> 32,332,096 total

    hipMemsetAsync(cnt, 0, N_NODES * sizeof(int), stream);
    prep_kernel<<<256 + HIST_B + OUTZ_B, 256, 0, stream>>>(W1, W2, W3, eidx,
        W1t, Wat, Wbt, W3t, cnt, (u32x4*)d_out);
    scanA_kernel<<<SCAN_B, 256, 0, stream>>>(cnt, aux);
    scatter_node_kernel<<<HIST_B + NODE_B, 256, 0, stream>>>(eidx, cnt, aux, spair,
        x, W1t, Wat, Wbt, b1, b2, gA, gB);
    edge_kernel<<<2048, 256, 0, stream>>>(gA, gB, spair, W3t, b3, (unsigned int*)d_out);
}

// Round 11
// 283.813 us; speedup vs baseline: 1.6510x; 1.0327x over previous
//
#include <hip/hip_runtime.h>
#include <hip/hip_bf16.h>

#define N_NODES 50000
#define N_EDGES 800000
#define DIM 128
#define NTILES (N_EDGES / 64)   // 12500 exactly
#define SCAN_B 196              // ceil(50000/256)
#define HIST_B 3125             // 800000/256
#define NODE_B 782              // ceil(50000/64)
#define OUTZ_B 512

typedef __bf16 bf16x8 __attribute__((ext_vector_type(8)));
typedef float f32x4 __attribute__((ext_vector_type(4)));
typedef unsigned int u32x4 __attribute__((ext_vector_type(4)));

__device__ __forceinline__ unsigned short f2bf(float f) {
    unsigned u = __float_as_uint(f);
    u += 0x7fffu + ((u >> 16) & 1u);          // round-to-nearest-even
    return (unsigned short)(u >> 16);
}
__device__ __forceinline__ float bf2f(unsigned short s) {
    return __uint_as_float(((unsigned)s) << 16);
}
// hw-packed f32x2 -> bf16x2 (v_cvt_pk_bf16_f32 on gfx950), lo in low 16 bits
__device__ __forceinline__ unsigned pack_bf2(float lo, float hi) {
    __hip_bfloat162 h = __float22bfloat162_rn(make_float2(lo, hi));
    unsigned u;
    __builtin_memcpy(&u, &h, 4);              // bit_cast fails: type not trivially copyable
    return u;
}
__device__ __forceinline__ unsigned short f2bf_hw(float f) {
    __hip_bfloat16 h = __float2bfloat16(f);
    unsigned short s;
    __builtin_memcpy(&s, &h, 2);
    return s;
}

// ---- K1: convert weights (blocks 0..255) + dst hist (256..3380) + zero out (rest)
__global__ void prep_kernel(const float* __restrict__ W1, const float* __restrict__ W2,
                            const float* __restrict__ W3, const int* __restrict__ eidx,
                            unsigned short* __restrict__ W1t, unsigned short* __restrict__ Wat,
                            unsigned short* __restrict__ Wbt, unsigned short* __restrict__ W3t,
                            int* __restrict__ cnt, u32x4* __restrict__ outz) {
    int bid = blockIdx.x, tid = threadIdx.x;
    if (bid < 256) {
        int i = bid * 256 + tid;
        int j = i & (DIM * DIM - 1);
        int k = j >> 7, n = j & 127;
        int sec = i >> 14;
        if (sec == 0)      W1t[n * 128 + k] = f2bf(W1[k * 128 + n]);
        else if (sec == 1) Wat[n * 128 + k] = f2bf(W2[k * 128 + n] - W2[(k + 128) * 128 + n]);
        else if (sec == 2) Wbt[n * 128 + k] = f2bf(W2[(k + 128) * 128 + n]);
        else               W3t[n * 128 + k] = f2bf(W3[k * 128 + n]);
    } else if (bid < 256 + HIST_B) {
        int e = (bid - 256) * 256 + tid;      // exactly covers 800000
        atomicAdd(&cnt[eidx[N_EDGES + e]], 1);
    } else {
        int b = bid - 256 - HIST_B;
        u32x4 z = (u32x4){0u, 0u, 0u, 0u};
        for (int i = b * 256 + tid; i < N_NODES * DIM / 4; i += OUTZ_B * 256) outz[i] = z;
    }
}

// ---- K2: per-chunk exclusive scan of cnt + chunk totals
__global__ void scanA_kernel(int* __restrict__ cnt, int* __restrict__ aux) {
    __shared__ int buf[256];
    int t = threadIdx.x, i = blockIdx.x * 256 + t;
    int v = (i < N_NODES) ? cnt[i] : 0;
    buf[t] = v;
    __syncthreads();
    for (int off = 1; off < 256; off <<= 1) {
        int u = (t >= off) ? buf[t - off] : 0;
        __syncthreads();
        buf[t] += u;
        __syncthreads();
    }
    if (i < N_NODES) cnt[i] = buf[t] - v;
    if (t == 255) aux[blockIdx.x] = buf[255];
}

// ---- K3: scatter (blocks 0..3124) + node GEMMs (blocks 3125..3906)
// node part: h = bf16(x@W1+b1) -> LDS -> gA = bf16(h@Wa + b2), gB = bf16(h@Wb)
// where Wa = W2a - W2b, Wb = W2b, so edge m1 = relu(gA[dst] + gB[src]).
__global__ __launch_bounds__(256, 2) void scatter_node_kernel(
        const int* __restrict__ eidx, int* __restrict__ cursor, const int* __restrict__ aux,
        int2* __restrict__ spair,
        const float* __restrict__ x, const unsigned short* __restrict__ W1t,
        const unsigned short* __restrict__ Wat, const unsigned short* __restrict__ Wbt,
        const float* __restrict__ b1, const float* __restrict__ b2,
        unsigned short* __restrict__ gA, unsigned short* __restrict__ gB) {
    __shared__ __align__(16) unsigned short w1t[128 * 136];   // also scan buf for scatter path
    __shared__ __align__(16) unsigned short h_lds[64 * 136];
    int tid = threadIdx.x, bid = blockIdx.x;
    if (bid < HIST_B) {
        int* buf = (int*)w1t;
        int v = (tid < SCAN_B) ? aux[tid] : 0;
        buf[tid] = v;
        __syncthreads();
        for (int off = 1; off < 256; off <<= 1) {
            int u = (tid >= off) ? buf[tid - off] : 0;
            __syncthreads();
            buf[tid] += u;
            __syncthreads();
        }
        int excl = buf[tid] - v;
        __syncthreads();
        buf[tid] = excl;
        __syncthreads();
        int e = bid * 256 + tid;                  // exactly covers 800000
        int d = eidx[N_EDGES + e];
        int p = atomicAdd(&cursor[d], 1) + buf[d >> 8];
        long long pv;
        int2 pv2 = make_int2(eidx[e], d);
        __builtin_memcpy(&pv, &pv2, 8);
        __builtin_nontemporal_store(pv, (long long*)&spair[p]);
        return;
    }
    // ---- node path
    int bl = bid - HIST_B;
    #pragma unroll
    for (int it = 0; it < 8; it++) {
        int idx = (tid + it * 256) * 8;
        int n = idx >> 7, k = idx & 127;
        *(u32x4*)(&w1t[n * 136 + k]) = *(const u32x4*)(&W1t[idx]);
    }
    int w = tid >> 6, lane = tid & 63;
    int lr = lane & 15, q = lane >> 4;
    bf16x8 baf[2][4], bbf[2][4];
    float b2v[2];
    #pragma unroll
    for (int ct = 0; ct < 2; ct++) {
        int n = (2 * w + ct) * 16 + lr;
        #pragma unroll
        for (int kt = 0; kt < 4; kt++) {
            baf[ct][kt] = __builtin_bit_cast(bf16x8, *(const u32x4*)(&Wat[n * 128 + kt * 32 + q * 8]));
            bbf[ct][kt] = __builtin_bit_cast(bf16x8, *(const u32x4*)(&Wbt[n * 128 + kt * 32 + q * 8]));
        }
        b2v[ct] = b2[n];
    }
    __syncthreads();
    // stage 1: h rows (wave w: rows w*16..w*16+15 of this 64-row tile)
    int row0 = bl * 64;
    int rowA = row0 + w * 16 + lr; if (rowA >= N_NODES) rowA = N_NODES - 1;
    {
        f32x4 acc[8];
        #pragma unroll
        for (int ct = 0; ct < 8; ct++) acc[ct] = (f32x4){0.f, 0.f, 0.f, 0.f};
        #pragma unroll
        for (int kt = 0; kt < 4; kt++) {
            const float* ap = x + (size_t)rowA * DIM + kt * 32 + q * 8;
            f32x4 x0 = *(const f32x4*)(ap);
            f32x4 x1 = *(const f32x4*)(ap + 4);
            bf16x8 a;
            #pragma unroll
            for (int j = 0; j < 4; j++) { a[j] = (__bf16)x0[j]; a[j + 4] = (__bf16)x1[j]; }
            #pragma unroll
            for (int ct = 0; ct < 8; ct++) {
                bf16x8 b = __builtin_bit_cast(bf16x8,
                    *(const u32x4*)(&w1t[(ct * 16 + lr) * 136 + kt * 32 + q * 8]));
                acc[ct] = __builtin_amdgcn_mfma_f32_16x16x32_bf16(a, b, acc[ct], 0, 0, 0);
            }
        }
        #pragma unroll
        for (int ct = 0; ct < 8; ct++) {
            int col = ct * 16 + lr;
            float bias = b1[col];
            #pragma unroll
            for (int r = 0; r < 4; r++)   // C/D: col=lane&15, row=quad*4+reg
                h_lds[(w * 16 + q * 4 + r) * 136 + col] = f2bf(acc[ct][r] + bias);
        }
    }
    __syncthreads();
    // stage 2: gA/gB = h @ Wa|Wb over all 64 rows, wave's 32 cols
    {
        f32x4 accA[4][2], accB[4][2];
        #pragma unroll
        for (int rt = 0; rt < 4; rt++)
            #pragma unroll
            for (int ct = 0; ct < 2; ct++) {
                accA[rt][ct] = (f32x4){0.f, 0.f, 0.f, 0.f};
                accB[rt][ct] = (f32x4){0.f, 0.f, 0.f, 0.f};
            }
        #pragma unroll
        for (int kt = 0; kt < 4; kt++) {
            #pragma unroll
            for (int rt = 0; rt < 4; rt++) {
                bf16x8 a = __builtin_bit_cast(bf16x8,
                    *(const u32x4*)(&h_lds[(rt * 16 + lr) * 136 + kt * 32 + q * 8]));
                accA[rt][0] = __builtin_amdgcn_mfma_f32_16x16x32_bf16(a, baf[0][kt], accA[rt][0], 0, 0, 0);
                accA[rt][1] = __builtin_amdgcn_mfma_f32_16x16x32_bf16(a, baf[1][kt], accA[rt][1], 0, 0, 0);
                accB[rt][0] = __builtin_amdgcn_mfma_f32_16x16x32_bf16(a, bbf[0][kt], accB[rt][0], 0, 0, 0);
                accB[rt][1] = __builtin_amdgcn_mfma_f32_16x16x32_bf16(a, bbf[1][kt], accB[rt][1], 0, 0, 0);
            }
        }
        #pragma unroll
        for (int rt = 0; rt < 4; rt++) {
            #pragma unroll
            for (int ct = 0; ct < 2; ct++) {
                int col = (2 * w + ct) * 16 + lr;
                #pragma unroll
                for (int r = 0; r < 4; r++) {
                    int row = row0 + rt * 16 + q * 4 + r;
                    if (row < N_NODES) {
                        gA[(size_t)row * DIM + col] = f2bf(accA[rt][ct][r] + b2v[ct]);
                        gB[(size_t)row * DIM + col] = f2bf(accB[rt][ct][r]);
                    }
                }
            }
        }
    }
}

// ---- K4: edge = relu(gA[dst]+gB[src]) -> GEMM2 -> segmented scatter-max
// 2 barriers/tile (s_dst double-buffered; barrier(1) of iter t+1 orders segmax(t)
// before m2 writes(t+1); m1 writes are disjoint from segmax's m2/s_dst reads).
__global__ __launch_bounds__(256, 4) void edge_kernel(
        const unsigned short* __restrict__ gA,
        const unsigned short* __restrict__ gB,
        const int2* __restrict__ spair,
        const unsigned short* __restrict__ W3t,
        const float* __restrict__ b3,
        unsigned int* __restrict__ out) {
    __shared__ __align__(16) unsigned short m1_lds[64 * 136];   // bf16 m1
    __shared__ __align__(16) unsigned short m2_lds[64 * 136];   // bf16 m2
    __shared__ int s_dst[2][64];                                 // double-buffered

    int tid = threadIdx.x;
    int w = tid >> 6, lane = tid & 63;
    int lr = lane & 15, q = lane >> 4;
    int tr = tid >> 4;             // tile-row group 0..15
    int c = (tid & 15) * 8;        // col chunk (shorts)

    bf16x8 b3f[2][4];
    float b3v[2];
    #pragma unroll
    for (int ct = 0; ct < 2; ct++) {
        int n = (2 * w + ct) * 16 + lr;
        #pragma unroll
        for (int kt = 0; kt < 4; kt++)
            b3f[ct][kt] = __builtin_bit_cast(bf16x8, *(const u32x4*)(&W3t[n * 128 + kt * 32 + q * 8]));
        b3v[ct] = b3[n];
    }

    int tb = blockIdx.x;
    int sel = 0;
    int2 pr[4];
    {
        int eb = tb * 64;
        #pragma unroll
        for (int it = 0; it < 4; it++) pr[it] = spair[eb + tr + 16 * it];
    }

    for (; tb < NTILES; tb += gridDim.x) {
        // m1[t][c..c+7] = relu(gA[dst_t] + gB[src_t])  — hw bf16x2 pack
        #pragma unroll
        for (int it = 0; it < 4; it++) {
            int t = tr + 16 * it;
            u32x4 ga = *(const u32x4*)(&gA[(size_t)pr[it].y * DIM + c]);
            u32x4 gb = *(const u32x4*)(&gB[(size_t)pr[it].x * DIM + c]);
            u32x4 m;
            #pragma unroll
            for (int jj = 0; jj < 4; jj++) {
                float lo = __uint_as_float(ga[jj] << 16) + __uint_as_float(gb[jj] << 16);
                float hi = __uint_as_float(ga[jj] & 0xffff0000u) + __uint_as_float(gb[jj] & 0xffff0000u);
                m[jj] = pack_bf2(fmaxf(lo, 0.f), fmaxf(hi, 0.f));
            }
            *(u32x4*)(&m1_lds[t * 136 + c]) = m;
        }
        if ((tid & 15) == 0) {
            #pragma unroll
            for (int it = 0; it < 4; it++) s_dst[sel][tr + 16 * it] = pr[it].y;
        }
        __syncthreads();   // (1) m1 ready; also guarantees segmax(t-1) fully done

        // prefetch next tile's indices
        int nx = tb + (int)gridDim.x;
        int2 npr[4];
        if (nx < NTILES) {
            int eb = nx * 64;
            #pragma unroll
            for (int it = 0; it < 4; it++) npr[it] = spair[eb + tr + 16 * it];
        }

        // GEMM2: m2 = relu(m1 @ W3 + b3)
        f32x4 acc2[4][2];
        #pragma unroll
        for (int rt = 0; rt < 4; rt++)
            #pragma unroll
            for (int ct = 0; ct < 2; ct++) acc2[rt][ct] = (f32x4){0.f, 0.f, 0.f, 0.f};
        #pragma unroll
        for (int kt = 0; kt < 4; kt++) {
            #pragma unroll
            for (int rt = 0; rt < 4; rt++) {
                bf16x8 a = __builtin_bit_cast(bf16x8,
                    *(const u32x4*)(&m1_lds[(rt * 16 + lr) * 136 + kt * 32 + q * 8]));
                acc2[rt][0] = __builtin_amdgcn_mfma_f32_16x16x32_bf16(a, b3f[0][kt], acc2[rt][0], 0, 0, 0);
                acc2[rt][1] = __builtin_amdgcn_mfma_f32_16x16x32_bf16(a, b3f[1][kt], acc2[rt][1], 0, 0, 0);
            }
        }
        #pragma unroll
        for (int rt = 0; rt < 4; rt++) {
            #pragma unroll
            for (int ct = 0; ct < 2; ct++) {
                int col = (2 * w + ct) * 16 + lr;
                #pragma unroll
                for (int r = 0; r < 4; r++)
                    m2_lds[(rt * 16 + q * 4 + r) * 136 + col] = f2bf_hw(fmaxf(acc2[rt][ct][r] + b3v[ct], 0.f));
            }
        }
        __syncthreads();   // (2) m2 ready

        // segmented max over sorted dst runs: thread -> (col = tid&127, rows r0..r0+31)
        {
            int col = tid & 127;
            int r0 = (tid >> 7) * 32;
            float cur = bf2f(m2_lds[r0 * 136 + col]);
            int d = s_dst[sel][r0];                 // wave-uniform
            #pragma unroll 4
            for (int i = 1; i < 32; i++) {
                int dn = s_dst[sel][r0 + i];        // wave-uniform
                float v = bf2f(m2_lds[(r0 + i) * 136 + col]);
                if (dn != d) {                      // wave-uniform branch
                    atomicMax(&out[(size_t)d * DIM + col], __float_as_uint(cur));
                    d = dn; cur = v;
                } else {
                    cur = fmaxf(cur, v);
                }
            }
            atomicMax(&out[(size_t)d * DIM + col], __float_as_uint(cur));
        }
        // no trailing barrier: next iter's m1/s_dst[sel^1] writes don't touch m2/s_dst[sel]

        sel ^= 1;
        #pragma unroll
        for (int it = 0; it < 4; it++) pr[it] = npr[it];
    }
}

extern "C" void kernel_launch(void* const* d_in, const int* in_sizes, int n_in,
                              void* d_out, int out_size, void* d_ws, size_t ws_size,
                              hipStream_t stream) {
    const float* x  = (const float*)d_in[0];
    const int* eidx = (const int*)d_in[1];
    const float* W1 = (const float*)d_in[2];
    const float* b1 = (const float*)d_in[3];
    const float* W2 = (const float*)d_in[4];
    const float* b2 = (const float*)d_in[5];
    const float* W3 = (const float*)d_in[6];
    const float* b3 = (const float*)d_in[7];

    char* ws = (char*)d_ws;
    unsigned short* gA  = (unsigned short*)ws;                     // 12,800,000 B
    unsigned short* gB  = (unsigned short*)(ws + 12800000);        // 12,800,000 B
    unsigned short* W1t = (unsigned short*)(ws + 25600000);        // 32,768 B
    unsigned short* Wat = (unsigned short*)(ws + 25632768);        // 32,768 B
    unsigned short* Wbt = (unsigned short*)(ws + 25665536);        // 32,768 B
    unsigned short* W3t = (unsigned short*)(ws + 25698304);        // 32,768 B
    int* cnt            = (int*)(ws + 25731072);                   // 200,000 B
    int* aux            = (int*)(ws + 25931072);                   // 1,024 B
    int2* spair         = (int2*)(ws + 25932096);                  // 6,400,000 B -> 32,332,096 total

    (void)hipMemsetAsync(cnt, 0, N_NODES * sizeof(int), stream);
    prep_kernel<<<256 + HIST_B + OUTZ_B, 256, 0, stream>>>(W1, W2, W3, eidx,
        W1t, Wat, Wbt, W3t, cnt, (u32x4*)d_out);
    scanA_kernel<<<SCAN_B, 256, 0, stream>>>(cnt, aux);
    scatter_node_kernel<<<HIST_B + NODE_B, 256, 0, stream>>>(eidx, cnt, aux, spair,
        x, W1t, Wat, Wbt, b1, b2, gA, gB);
    edge_kernel<<<2048, 256, 0, stream>>>(gA, gB, spair, W3t, b3, (unsigned int*)d_out);
}

// Round 12
// 262.706 us; speedup vs baseline: 1.7836x; 1.0803x over previous
//
#include <hip/hip_runtime.h>
#include <hip/hip_bf16.h>

#define N_NODES 50000
#define N_EDGES 800000
#define DIM 128
#define NTILES (N_EDGES / 64)   // 12500 exactly
#define SCAN_B 196              // ceil(50000/256)
#define HIST_B 3125             // 800000/256
#define NODE_B 782              // ceil(50000/64)
#define OUTZ_B 512
#define SCAT_B 2048             // 8 sets x 256 blocks; set = bid&7 -> XCD heuristic

typedef __bf16 bf16x8 __attribute__((ext_vector_type(8)));
typedef float f32x4 __attribute__((ext_vector_type(4)));
typedef unsigned int u32x4 __attribute__((ext_vector_type(4)));

__device__ __forceinline__ unsigned short f2bf(float f) {
    unsigned u = __float_as_uint(f);
    u += 0x7fffu + ((u >> 16) & 1u);          // round-to-nearest-even
    return (unsigned short)(u >> 16);
}
__device__ __forceinline__ float bf2f(unsigned short s) {
    return __uint_as_float(((unsigned)s) << 16);
}
// hw-packed f32x2 -> bf16x2 (v_cvt_pk_bf16_f32 on gfx950), lo in low 16 bits
__device__ __forceinline__ unsigned pack_bf2(float lo, float hi) {
    __hip_bfloat162 h = __float22bfloat162_rn(make_float2(lo, hi));
    unsigned u;
    __builtin_memcpy(&u, &h, 4);              // bit_cast fails: type not trivially copyable
    return u;
}
__device__ __forceinline__ unsigned short f2bf_hw(float f) {
    __hip_bfloat16 h = __float2bfloat16(f);
    unsigned short s;
    __builtin_memcpy(&s, &h, 2);
    return s;
}

// ---- K1: convert weights (blocks 0..255) + dst hist (256..3380) + zero out (rest)
__global__ void prep_kernel(const float* __restrict__ W1, const float* __restrict__ W2,
                            const float* __restrict__ W3, const int* __restrict__ eidx,
                            unsigned short* __restrict__ W1t, unsigned short* __restrict__ Wat,
                            unsigned short* __restrict__ Wbt, unsigned short* __restrict__ W3t,
                            int* __restrict__ cnt, u32x4* __restrict__ outz) {
    int bid = blockIdx.x, tid = threadIdx.x;
    if (bid < 256) {
        int i = bid * 256 + tid;
        int j = i & (DIM * DIM - 1);
        int k = j >> 7, n = j & 127;
        int sec = i >> 14;
        if (sec == 0)      W1t[n * 128 + k] = f2bf(W1[k * 128 + n]);
        else if (sec == 1) Wat[n * 128 + k] = f2bf(W2[k * 128 + n] - W2[(k + 128) * 128 + n]);
        else if (sec == 2) Wbt[n * 128 + k] = f2bf(W2[(k + 128) * 128 + n]);
        else               W3t[n * 128 + k] = f2bf(W3[k * 128 + n]);
    } else if (bid < 256 + HIST_B) {
        int e = (bid - 256) * 256 + tid;      // exactly covers 800000
        atomicAdd(&cnt[eidx[N_EDGES + e]], 1);
    } else {
        int b = bid - 256 - HIST_B;
        u32x4 z = (u32x4){0u, 0u, 0u, 0u};
        for (int i = b * 256 + tid; i < N_NODES * DIM / 4; i += OUTZ_B * 256) outz[i] = z;
    }
}

// ---- K2: scanA (blocks 0..195) + node GEMMs (blocks 196..977)
// node: h = bf16(x@W1+b1) -> LDS -> gA = bf16(h@Wa + b2), gB = bf16(h@Wb)
// where Wa = W2a - W2b, Wb = W2b, so edge m1 = relu(gA[dst] + gB[src]).
__global__ __launch_bounds__(256, 2) void scan_node_kernel(
        int* __restrict__ cnt, int* __restrict__ aux,
        const float* __restrict__ x, const unsigned short* __restrict__ W1t,
        const unsigned short* __restrict__ Wat, const unsigned short* __restrict__ Wbt,
        const float* __restrict__ b1, const float* __restrict__ b2,
        unsigned short* __restrict__ gA, unsigned short* __restrict__ gB) {
    __shared__ __align__(16) unsigned short w1t[128 * 136];   // head doubles as scan buf
    __shared__ __align__(16) unsigned short h_lds[64 * 136];
    int tid = threadIdx.x, bid = blockIdx.x;
    if (bid < SCAN_B) {
        // per-chunk exclusive scan of cnt + chunk totals to aux
        int* buf = (int*)w1t;
        int i = bid * 256 + tid;
        int v = (i < N_NODES) ? cnt[i] : 0;
        buf[tid] = v;
        __syncthreads();
        for (int off = 1; off < 256; off <<= 1) {
            int u = (tid >= off) ? buf[tid - off] : 0;
            __syncthreads();
            buf[tid] += u;
            __syncthreads();
        }
        if (i < N_NODES) cnt[i] = buf[tid] - v;
        if (tid == 255) aux[bid] = buf[255];
        return;
    }
    // ---- node path
    int bl = bid - SCAN_B;
    #pragma unroll
    for (int it = 0; it < 8; it++) {
        int idx = (tid + it * 256) * 8;
        int n = idx >> 7, k = idx & 127;
        *(u32x4*)(&w1t[n * 136 + k]) = *(const u32x4*)(&W1t[idx]);
    }
    int w = tid >> 6, lane = tid & 63;
    int lr = lane & 15, q = lane >> 4;
    bf16x8 baf[2][4], bbf[2][4];
    float b2v[2];
    #pragma unroll
    for (int ct = 0; ct < 2; ct++) {
        int n = (2 * w + ct) * 16 + lr;
        #pragma unroll
        for (int kt = 0; kt < 4; kt++) {
            baf[ct][kt] = __builtin_bit_cast(bf16x8, *(const u32x4*)(&Wat[n * 128 + kt * 32 + q * 8]));
            bbf[ct][kt] = __builtin_bit_cast(bf16x8, *(const u32x4*)(&Wbt[n * 128 + kt * 32 + q * 8]));
        }
        b2v[ct] = b2[n];
    }
    __syncthreads();
    // stage 1: h rows (wave w: rows w*16..w*16+15 of this 64-row tile)
    int row0 = bl * 64;
    int rowA = row0 + w * 16 + lr; if (rowA >= N_NODES) rowA = N_NODES - 1;
    {
        f32x4 acc[8];
        #pragma unroll
        for (int ct = 0; ct < 8; ct++) acc[ct] = (f32x4){0.f, 0.f, 0.f, 0.f};
        #pragma unroll
        for (int kt = 0; kt < 4; kt++) {
            const float* ap = x + (size_t)rowA * DIM + kt * 32 + q * 8;
            f32x4 x0 = *(const f32x4*)(ap);
            f32x4 x1 = *(const f32x4*)(ap + 4);
            bf16x8 a;
            #pragma unroll
            for (int j = 0; j < 4; j++) { a[j] = (__bf16)x0[j]; a[j + 4] = (__bf16)x1[j]; }
            #pragma unroll
            for (int ct = 0; ct < 8; ct++) {
                bf16x8 b = __builtin_bit_cast(bf16x8,
                    *(const u32x4*)(&w1t[(ct * 16 + lr) * 136 + kt * 32 + q * 8]));
                acc[ct] = __builtin_amdgcn_mfma_f32_16x16x32_bf16(a, b, acc[ct], 0, 0, 0);
            }
        }
        #pragma unroll
        for (int ct = 0; ct < 8; ct++) {
            int col = ct * 16 + lr;
            float bias = b1[col];
            #pragma unroll
            for (int r = 0; r < 4; r++)   // C/D: col=lane&15, row=quad*4+reg
                h_lds[(w * 16 + q * 4 + r) * 136 + col] = f2bf(acc[ct][r] + bias);
        }
    }
    __syncthreads();
    // stage 2: gA/gB = h @ Wa|Wb over all 64 rows, wave's 32 cols
    {
        f32x4 accA[4][2], accB[4][2];
        #pragma unroll
        for (int rt = 0; rt < 4; rt++)
            #pragma unroll
            for (int ct = 0; ct < 2; ct++) {
                accA[rt][ct] = (f32x4){0.f, 0.f, 0.f, 0.f};
                accB[rt][ct] = (f32x4){0.f, 0.f, 0.f, 0.f};
            }
        #pragma unroll
        for (int kt = 0; kt < 4; kt++) {
            #pragma unroll
            for (int rt = 0; rt < 4; rt++) {
                bf16x8 a = __builtin_bit_cast(bf16x8,
                    *(const u32x4*)(&h_lds[(rt * 16 + lr) * 136 + kt * 32 + q * 8]));
                accA[rt][0] = __builtin_amdgcn_mfma_f32_16x16x32_bf16(a, baf[0][kt], accA[rt][0], 0, 0, 0);
                accA[rt][1] = __builtin_amdgcn_mfma_f32_16x16x32_bf16(a, baf[1][kt], accA[rt][1], 0, 0, 0);
                accB[rt][0] = __builtin_amdgcn_mfma_f32_16x16x32_bf16(a, bbf[0][kt], accB[rt][0], 0, 0, 0);
                accB[rt][1] = __builtin_amdgcn_mfma_f32_16x16x32_bf16(a, bbf[1][kt], accB[rt][1], 0, 0, 0);
            }
        }
        #pragma unroll
        for (int rt = 0; rt < 4; rt++) {
            #pragma unroll
            for (int ct = 0; ct < 2; ct++) {
                int col = (2 * w + ct) * 16 + lr;
                #pragma unroll
                for (int r = 0; r < 4; r++) {
                    int row = row0 + rt * 16 + q * 4 + r;
                    if (row < N_NODES) {
                        gA[(size_t)row * DIM + col] = f2bf(accA[rt][ct][r] + b2v[ct]);
                        gB[(size_t)row * DIM + col] = f2bf(accB[rt][ct][r]);
                    }
                }
            }
        }
    }
}

// ---- K3: XCD-binned scatter. Set = bid&7 handles dsts with (d>>8)&7 == set, so
// cnt[d] atomic lines and spair[p] regions are XCD-local (lines assemble fully in
// one L2, write back once sequentially — kills the 51MB partial-line writeback).
__global__ __launch_bounds__(256) void scatter_kernel(
        const int* __restrict__ eidx, int* __restrict__ cursor, const int* __restrict__ aux,
        int2* __restrict__ spair) {
    __shared__ int buf[256];
    int tid = threadIdx.x, bid = blockIdx.x;
    // local exclusive scan of aux[196] -> chunk base offsets
    int v = (tid < SCAN_B) ? aux[tid] : 0;
    buf[tid] = v;
    __syncthreads();
    for (int off = 1; off < 256; off <<= 1) {
        int u = (tid >= off) ? buf[tid - off] : 0;
        __syncthreads();
        buf[tid] += u;
        __syncthreads();
    }
    int excl = buf[tid] - v;
    __syncthreads();
    buf[tid] = excl;
    __syncthreads();
    int set = bid & 7;                        // target XCD (dispatch-heuristic; perf-only)
    int j = bid >> 3;                         // 0..255 within set
    for (int e = j * 256 + tid; e < N_EDGES; e += (SCAT_B / 8) * 256) {
        int d = eidx[N_EDGES + e];            // coalesced; read by all sets (read-shared)
        if (((d >> 8) & 7) == set) {
            int s = eidx[e];
            int p = atomicAdd(&cursor[d], 1) + buf[d >> 8];
            spair[p] = make_int2(s, d);       // XCD-local region
        }
    }
}

// ---- K4: edge = relu(gA[dst]+gB[src]) -> GEMM2 -> segmented scatter-max
// 2 barriers/tile (s_dst double-buffered; barrier(1) of iter t+1 orders segmax(t)
// before m2 writes(t+1); m1 writes are disjoint from segmax's m2/s_dst reads).
__global__ __launch_bounds__(256, 4) void edge_kernel(
        const unsigned short* __restrict__ gA,
        const unsigned short* __restrict__ gB,
        const int2* __restrict__ spair,
        const unsigned short* __restrict__ W3t,
        const float* __restrict__ b3,
        unsigned int* __restrict__ out) {
    __shared__ __align__(16) unsigned short m1_lds[64 * 136];   // bf16 m1
    __shared__ __align__(16) unsigned short m2_lds[64 * 136];   // bf16 m2
    __shared__ int s_dst[2][64];                                 // double-buffered

    int tid = threadIdx.x;
    int w = tid >> 6, lane = tid & 63;
    int lr = lane & 15, q = lane >> 4;
    int tr = tid >> 4;             // tile-row group 0..15
    int c = (tid & 15) * 8;        // col chunk (shorts)

    bf16x8 b3f[2][4];
    float b3v[2];
    #pragma unroll
    for (int ct = 0; ct < 2; ct++) {
        int n = (2 * w + ct) * 16 + lr;
        #pragma unroll
        for (int kt = 0; kt < 4; kt++)
            b3f[ct][kt] = __builtin_bit_cast(bf16x8, *(const u32x4*)(&W3t[n * 128 + kt * 32 + q * 8]));
        b3v[ct] = b3[n];
    }

    int tb = blockIdx.x;
    int sel = 0;
    int2 pr[4];
    {
        int eb = tb * 64;
        #pragma unroll
        for (int it = 0; it < 4; it++) pr[it] = spair[eb + tr + 16 * it];
    }

    for (; tb < NTILES; tb += gridDim.x) {
        // m1[t][c..c+7] = relu(gA[dst_t] + gB[src_t])  — hw bf16x2 pack
        #pragma unroll
        for (int it = 0; it < 4; it++) {
            int t = tr + 16 * it;
            u32x4 ga = *(const u32x4*)(&gA[(size_t)pr[it].y * DIM + c]);
            u32x4 gb = *(const u32x4*)(&gB[(size_t)pr[it].x * DIM + c]);
            u32x4 m;
            #pragma unroll
            for (int jj = 0; jj < 4; jj++) {
                float lo = __uint_as_float(ga[jj] << 16) + __uint_as_float(gb[jj] << 16);
                float hi = __uint_as_float(ga[jj] & 0xffff0000u) + __uint_as_float(gb[jj] & 0xffff0000u);
                m[jj] = pack_bf2(fmaxf(lo, 0.f), fmaxf(hi, 0.f));
            }
            *(u32x4*)(&m1_lds[t * 136 + c]) = m;
        }
        if ((tid & 15) == 0) {
            #pragma unroll
            for (int it = 0; it < 4; it++) s_dst[sel][tr + 16 * it] = pr[it].y;
        }
        __syncthreads();   // (1) m1 ready; also guarantees segmax(t-1) fully done

        // prefetch next tile's indices
        int nx = tb + (int)gridDim.x;
        int2 npr[4];
        if (nx < NTILES) {
            int eb = nx * 64;
            #pragma unroll
            for (int it = 0; it < 4; it++) npr[it] = spair[eb + tr + 16 * it];
        }

        // GEMM2: m2 = relu(m1 @ W3 + b3)
        f32x4 acc2[4][2];
        #pragma unroll
        for (int rt = 0; rt < 4; rt++)
            #pragma unroll
            for (int ct = 0; ct < 2; ct++) acc2[rt][ct] = (f32x4){0.f, 0.f, 0.f, 0.f};
        #pragma unroll
        for (int kt = 0; kt < 4; kt++) {
            #pragma unroll
            for (int rt = 0; rt < 4; rt++) {
                bf16x8 a = __builtin_bit_cast(bf16x8,
                    *(const u32x4*)(&m1_lds[(rt * 16 + lr) * 136 + kt * 32 + q * 8]));
                acc2[rt][0] = __builtin_amdgcn_mfma_f32_16x16x32_bf16(a, b3f[0][kt], acc2[rt][0], 0, 0, 0);
                acc2[rt][1] = __builtin_amdgcn_mfma_f32_16x16x32_bf16(a, b3f[1][kt], acc2[rt][1], 0, 0, 0);
            }
        }
        #pragma unroll
        for (int rt = 0; rt < 4; rt++) {
            #pragma unroll
            for (int ct = 0; ct < 2; ct++) {
                int col = (2 * w + ct) * 16 + lr;
                #pragma unroll
                for (int r = 0; r < 4; r++)
                    m2_lds[(rt * 16 + q * 4 + r) * 136 + col] = f2bf_hw(fmaxf(acc2[rt][ct][r] + b3v[ct], 0.f));
            }
        }
        __syncthreads();   // (2) m2 ready

        // segmented max over sorted dst runs: thread -> (col = tid&127, rows r0..r0+31)
        {
            int col = tid & 127;
            int r0 = (tid >> 7) * 32;
            float cur = bf2f(m2_lds[r0 * 136 + col]);
            int d = s_dst[sel][r0];                 // wave-uniform
            #pragma unroll 4
            for (int i = 1; i < 32; i++) {
                int dn = s_dst[sel][r0 + i];        // wave-uniform
                float v = bf2f(m2_lds[(r0 + i) * 136 + col]);
                if (dn != d) {                      // wave-uniform branch
                    atomicMax(&out[(size_t)d * DIM + col], __float_as_uint(cur));
                    d = dn; cur = v;
                } else {
                    cur = fmaxf(cur, v);
                }
            }
            atomicMax(&out[(size_t)d * DIM + col], __float_as_uint(cur));
        }
        // no trailing barrier: next iter's m1/s_dst[sel^1] writes don't touch m2/s_dst[sel]

        sel ^= 1;
        #pragma unroll
        for (int it = 0; it < 4; it++) pr[it] = npr[it];
    }
}

extern "C" void kernel_launch(void* const* d_in, const int* in_sizes, int n_in,
                              void* d_out, int out_size, void* d_ws, size_t ws_size,
                              hipStream_t stream) {
    const float* x  = (const float*)d_in[0];
    const int* eidx = (const int*)d_in[1];
    const float* W1 = (const float*)d_in[2];
    const float* b1 = (const float*)d_in[3];
    const float* W2 = (const float*)d_in[4];
    const float* b2 = (const float*)d_in[5];
    const float* W3 = (const float*)d_in[6];
    const float* b3 = (const float*)d_in[7];

    char* ws = (char*)d_ws;
    unsigned short* gA  = (unsigned short*)ws;                     // 12,800,000 B
    unsigned short* gB  = (unsigned short*)(ws + 12800000);        // 12,800,000 B
    unsigned short* W1t = (unsigned short*)(ws + 25600000);        // 32,768 B
    unsigned short* Wat = (unsigned short*)(ws + 25632768);        // 32,768 B
    unsigned short* Wbt = (unsigned short*)(ws + 25665536);        // 32,768 B
    unsigned short* W3t = (unsigned short*)(ws + 25698304);        // 32,768 B
    int* cnt            = (int*)(ws + 25731072);                   // 200,000 B
    int* aux            = (int*)(ws + 25931072);                   // 1,024 B
    int2* spair         = (int2*)(ws + 25932096);                  // 6,400,000 B -> 32,332,096 total

    (void)hipMemsetAsync(cnt, 0, N_NODES * sizeof(int), stream);
    prep_kernel<<<256 + HIST_B + OUTZ_B, 256, 0, stream>>>(W1, W2, W3, eidx,
        W1t, Wat, Wbt, W3t, cnt, (u32x4*)d_out);
    scan_node_kernel<<<SCAN_B + NODE_B, 256, 0, stream>>>(cnt, aux,
        x, W1t, Wat, Wbt, b1, b2, gA, gB);
    scatter_kernel<<<SCAT_B, 256, 0, stream>>>(eidx, cnt, aux, spair);
    edge_kernel<<<2048, 256, 0, stream>>>(gA, gB, spair, W3t, b3, (unsigned int*)d_out);
}